// Round 5
// baseline (790.077 us; speedup 1.0000x reference)
//
#include <hip/hip_runtime.h>
#include <hip/hip_bf16.h>

// Problem constants
#define BB 32
#define TT 1500
#define TP 1536      // T padded to 12*128 for GEMM tiles
#define EE 512
#define HH 4
#define AA 512
#define NN 2048      // H*A
#define CC 10
#define KCONV 201
#define KAUG 576     // 512 enc + 40 conv + 24 zero pad (18 k-steps of 32)

typedef __attribute__((ext_vector_type(8))) __bf16 bf16x8;
typedef __attribute__((ext_vector_type(4))) float f32x4;

// ---------- helpers ----------
__device__ __forceinline__ unsigned short f2bf(float x) {
    unsigned int u = __float_as_uint(x);
    u = (u + 0x7fffu + ((u >> 16) & 1u)) >> 16;   // RNE, inputs always finite
    return (unsigned short)u;
}
__device__ __forceinline__ float bf2f(unsigned short u) {
    return __uint_as_float(((unsigned int)u) << 16);
}
__device__ __forceinline__ void glds16(const void* g, void* l) {
    __builtin_amdgcn_global_load_lds(
        (const __attribute__((address_space(1))) unsigned int*)g,
        (__attribute__((address_space(3))) unsigned int*)l, 16, 0, 0);
}
// tanh(x) = 1 - 2/(e^{2x}+1); saturates correctly at +-inf; abs err ~1e-6.
__device__ __forceinline__ float tanh_fast(float x) {
    float e = __expf(x * 2.0f);
    return fmaf(-2.0f, __builtin_amdgcn_rcpf(e + 1.0f), 1.0f);
}
// packed f32x2 -> bf16x2 (RNE)
__device__ __forceinline__ unsigned int pkbf(float x, float y) {
    float2 f{x, y};
    __hip_bfloat162 h2 = __float22bfloat162_rn(f);
    return *reinterpret_cast<unsigned int*>(&h2);
}
// split pair into packed hi bf16x2 and packed lo (residual) bf16x2
__device__ __forceinline__ void split2(float x, float y, unsigned int& h, unsigned int& l) {
    unsigned short hx = f2bf(x), hy = f2bf(y);
    h = ((unsigned int)hy << 16) | hx;
    l = pkbf(x - bf2f(hx), y - bf2f(hy));
}

// Fused prep kernel: block-range dispatch of 3 phases.
//   [0,1024)      dec   dec_a[b][n]  (4-way K-split + LDS reduce)
//   [1024,8704)   conv  grouped conv -> Chi/Clo[b][t][0..40)
//   [8704,8992)   wt    W planes (LDS-transposed, coalesced both sides)
#define PREP_DEC0   0
#define PREP_CONV0  1024
#define PREP_WT0    8704
#define PREP_TOTAL  8992

__global__ __launch_bounds__(256) void k_prep(
    const float* __restrict__ dec_out, const float* __restrict__ aw_step,
    const float* __restrict__ w_enc, const float* __restrict__ b_enc,
    const float* __restrict__ w_dec, const float* __restrict__ w_conv,
    const float* __restrict__ conv_k,
    unsigned short* __restrict__ Whi, unsigned short* __restrict__ Wlo,
    unsigned short* __restrict__ Chi, unsigned short* __restrict__ Clo,
    float* __restrict__ dec_a) {
    __shared__ float sh[64 * 65];   // wt transpose tile; aliased by dec/conv scratch
    const int bid = blockIdx.x;
    const int tid = threadIdx.x;

    if (bid < PREP_CONV0) {
        // ---- dec: dec_a[b][n] = b_enc[n] + sum_d dec[b][d]*w_dec[h][d][a] ----
        const int b  = bid >> 5;
        const int n0 = (bid & 31) * 64;
        const int n  = n0 + (tid & 63);
        const int dg = tid >> 6;                   // 0..3, 128 d each
        const int h  = n >> 9, a = n & 511;
        const float* dp = dec_out + (size_t)b * 512 + dg * 128;
        const float* wp = w_dec + ((size_t)h * 512 + dg * 128) * 512 + a;
        float acc = 0.f;
#pragma unroll 8
        for (int d = 0; d < 128; ++d) acc += dp[d] * wp[(size_t)d * 512];
        sh[tid] = acc;
        __syncthreads();
        if (tid < 64) {
            float tot = sh[tid] + sh[tid + 64] + sh[tid + 128] + sh[tid + 192];
            dec_a[(size_t)b * NN + n0 + tid] = b_enc[n0 + tid] + tot;
        }
    } else if (bid < PREP_WT0) {
        // ---- conv: grouped 1D conv over aw_step -> Chi/Clo[b][t][hc] ----
        int r = bid - PREP_CONV0;                  // 7680 = 6*40*32
        const int tch = r % 6;
        const int hc  = (r / 6) % 40;
        const int b   = r / 240;
        const int h   = hc / 10;
        const int t0  = tch * 256;
        float* sAw = sh;
        for (int i = tid; i < 456; i += 256) {
            int ts = t0 - 100 + i;
            sAw[i] = (ts >= 0 && ts < TT) ? aw_step[((size_t)b * TT + ts) * HH + h] : 0.f;
        }
        __syncthreads();
        int t = t0 + tid;
        if (t < TT) {
            const float* ck = conv_k + (size_t)hc * KCONV;   // uniform index -> s_load
            float acc = 0.f;
#pragma unroll 4
            for (int k = 0; k < KCONV; ++k) acc += sAw[tid + k] * ck[k];
            size_t o = ((size_t)b * TP + t) * 64 + hc;
            unsigned short hi = f2bf(acc);
            Chi[o] = hi; Clo[o] = f2bf(acc - bf2f(hi));
        }
    } else {
        // ---- wt: W planes [N=2048][KAUG], hi/lo; coalesced via LDS transpose ----
        int r = bid - PREP_WT0;                    // 0..287 = 4h * 8a * 9k
        const int h  = r / 72;
        const int rr = r % 72;
        const int at = rr / 9;
        const int kt = rr % 9;
        const int a0 = at * 64;
        if (kt < 8) {
            const int k0 = kt * 64;
#pragma unroll
            for (int it = 0; it < 16; ++it) {
                int kk = it * 4 + (tid >> 6);
                int aa = tid & 63;
                sh[kk * 65 + aa] = w_enc[((size_t)h * 512 + k0 + kk) * 512 + a0 + aa];
            }
            __syncthreads();
#pragma unroll
            for (int it = 0; it < 16; ++it) {
                int nl = it * 4 + (tid >> 6);
                int kk = tid & 63;
                float val = sh[kk * 65 + nl];
                size_t o = ((size_t)h * 512 + a0 + nl) * KAUG + k0 + kk;
                unsigned short hi = f2bf(val);
                Whi[o] = hi; Wlo[o] = f2bf(val - bf2f(hi));
            }
        } else {
            // k in [512,576): conv cols (block-diagonal per head) + zero pad
#pragma unroll
            for (int it = 0; it < 16; ++it) {
                int nl = it * 4 + (tid >> 6);
                int j  = tid & 63;
                float val = 0.f;
                if (j < 40 && (j / 10) == h)
                    val = w_conv[((size_t)h * 10 + (j % 10)) * 512 + a0 + nl];
                size_t o = ((size_t)h * 512 + a0 + nl) * KAUG + 512 + j;
                unsigned short hi = f2bf(val);
                Whi[o] = hi; Wlo[o] = f2bf(val - bf2f(hi));
            }
        }
    }
}

// ---------- fused MFMA GEMM (both paths) + (+dec_a, tanh, *v, reduce-A) -> energy ----------
// XCD-aware swizzle: 16 ntiles of one (m,b) land on one XCD (ids 8 apart) so the
// enc A-tile stays L2-resident across its 16 reuses.
// v-path (fully-valid tile): 1-product bf16, A staged directly from enc f32.
// p-path (tile has rows >= xlen, where *(-1024) amplifies error x1024): 3-product
// split-bf16 (hi*hi + hi*lo + lo*hi), hi/lo split computed in-register from enc.
__global__ __launch_bounds__(256) void k_gemm(
    const float* __restrict__ enc,
    const unsigned short* __restrict__ Chi, const unsigned short* __restrict__ Clo,
    const unsigned short* __restrict__ Whi, const unsigned short* __restrict__ Wlo,
    const float* __restrict__ dec_a, const float* __restrict__ vvec,
    const int* __restrict__ xl, float* __restrict__ energy) {
    __shared__ unsigned short lsAhi[4096], lsAlo[4096];
    __shared__ unsigned short lsBhi[4096], lsBlo[4096];
    const int id = blockIdx.x;                    // 6144 = 8 xcd * 16 n * 48 mb
    const int xcd = id & 7;
    const int wq  = id >> 3;
    const int ntile = wq & 15;
    const int mb = xcd * 48 + (wq >> 4);
    const int b = mb & 31, mtile = mb >> 5;
    const int tid = threadIdx.x;
    const int lane = tid & 63, wave = tid >> 6;
    const int wm = wave >> 1, wn = wave & 1;
    const int m0 = mtile * 128, n0 = ntile * 128;
    const int xlen = xl[b];

    f32x4 acc[4][4];
#pragma unroll
    for (int i = 0; i < 4; i++)
#pragma unroll
        for (int j = 0; j < 4; j++) acc[i][j] = (f32x4){0.f, 0.f, 0.f, 0.f};

    const int row = tid >> 2;
    const int ko  = (tid & 3) * 8;
    const size_t bbase = ((size_t)n0 + row) * KAUG + ko;
    const size_t cbase = ((size_t)b * TP + m0 + row) * 64 + ko;
    const int l1 = tid * 8;                       // bytes/16 per lane: wave-uniform + lane*16
    const int l2 = l1 + 2048;
    const int ar = wm * 64, br = wn * 64;
    const int fo = (lane & 15) * 32 + (lane >> 4) * 8;

    const float* ap0 = enc + ((size_t)b * TT + m0 + row) * 512 + ko;
    const float* ap1 = ap0 + (size_t)64 * 512;

    if (m0 + 128 <= xlen) {
        // ================= v-path: 1-product =================
        float4 fa0 = *(const float4*)(ap0);
        float4 fa1 = *(const float4*)(ap0 + 4);
        float4 fa2 = *(const float4*)(ap1);
        float4 fa3 = *(const float4*)(ap1 + 4);
        for (int ks = 0; ks < 18; ++ks) {
            const int k0 = ks * 32;
            __syncthreads();
            glds16(Whi + bbase + k0,                     &lsBhi[l1]);
            glds16(Whi + bbase + k0 + (size_t)64 * KAUG, &lsBhi[l2]);
            if (ks < 16) {
                uint4 w0, w1;
                w0.x = pkbf(fa0.x, fa0.y); w0.y = pkbf(fa0.z, fa0.w);
                w0.z = pkbf(fa1.x, fa1.y); w0.w = pkbf(fa1.z, fa1.w);
                w1.x = pkbf(fa2.x, fa2.y); w1.y = pkbf(fa2.z, fa2.w);
                w1.z = pkbf(fa3.x, fa3.y); w1.w = pkbf(fa3.z, fa3.w);
                *reinterpret_cast<uint4*>(&lsAhi[l1]) = w0;
                *reinterpret_cast<uint4*>(&lsAhi[l2]) = w1;
                if (ks < 15) {
                    const int nk = k0 + 32;
                    fa0 = *(const float4*)(ap0 + nk);
                    fa1 = *(const float4*)(ap0 + nk + 4);
                    fa2 = *(const float4*)(ap1 + nk);
                    fa3 = *(const float4*)(ap1 + nk + 4);
                }
            } else {
                glds16(Chi + cbase + (ks - 16) * 32,        &lsAhi[l1]);
                glds16(Chi + cbase + (ks - 16) * 32 + 4096, &lsAhi[l2]);
            }
            asm volatile("s_waitcnt vmcnt(0)" ::: "memory");
            __syncthreads();

            bf16x8 ah[4], bh[4];
#pragma unroll
            for (int i = 0; i < 4; i++) {
                ah[i] = *(const bf16x8*)&lsAhi[(ar + i * 16) * 32 + fo];
                bh[i] = *(const bf16x8*)&lsBhi[(br + i * 16) * 32 + fo];
            }
#pragma unroll
            for (int i = 0; i < 4; i++)
#pragma unroll
                for (int j = 0; j < 4; j++)
                    acc[i][j] = __builtin_amdgcn_mfma_f32_16x16x32_bf16(ah[i], bh[j], acc[i][j], 0, 0, 0);
        }
    } else {
        // ================= p-path: 3-product split-bf16 =================
        const bool g1 = (m0 + row + 64) < TT;     // rows >= 1500 fed zeros
        const float4 z4 = {0.f, 0.f, 0.f, 0.f};
        float4 fa0 = *(const float4*)(ap0);
        float4 fa1 = *(const float4*)(ap0 + 4);
        float4 fa2 = g1 ? *(const float4*)(ap1) : z4;
        float4 fa3 = g1 ? *(const float4*)(ap1 + 4) : z4;
        for (int ks = 0; ks < 18; ++ks) {
            const int k0 = ks * 32;
            __syncthreads();
            glds16(Whi + bbase + k0,                     &lsBhi[l1]);
            glds16(Whi + bbase + k0 + (size_t)64 * KAUG, &lsBhi[l2]);
            glds16(Wlo + bbase + k0,                     &lsBlo[l1]);
            glds16(Wlo + bbase + k0 + (size_t)64 * KAUG, &lsBlo[l2]);
            if (ks < 16) {
                uint4 h0, h1, e0, e1;
                split2(fa0.x, fa0.y, h0.x, e0.x); split2(fa0.z, fa0.w, h0.y, e0.y);
                split2(fa1.x, fa1.y, h0.z, e0.z); split2(fa1.z, fa1.w, h0.w, e0.w);
                split2(fa2.x, fa2.y, h1.x, e1.x); split2(fa2.z, fa2.w, h1.y, e1.y);
                split2(fa3.x, fa3.y, h1.z, e1.z); split2(fa3.z, fa3.w, h1.w, e1.w);
                *reinterpret_cast<uint4*>(&lsAhi[l1]) = h0;
                *reinterpret_cast<uint4*>(&lsAhi[l2]) = h1;
                *reinterpret_cast<uint4*>(&lsAlo[l1]) = e0;
                *reinterpret_cast<uint4*>(&lsAlo[l2]) = e1;
                if (ks < 15) {
                    const int nk = k0 + 32;
                    fa0 = *(const float4*)(ap0 + nk);
                    fa1 = *(const float4*)(ap0 + nk + 4);
                    fa2 = g1 ? *(const float4*)(ap1 + nk) : z4;
                    fa3 = g1 ? *(const float4*)(ap1 + nk + 4) : z4;
                }
            } else {
                glds16(Chi + cbase + (ks - 16) * 32,        &lsAhi[l1]);
                glds16(Chi + cbase + (ks - 16) * 32 + 4096, &lsAhi[l2]);
                glds16(Clo + cbase + (ks - 16) * 32,        &lsAlo[l1]);
                glds16(Clo + cbase + (ks - 16) * 32 + 4096, &lsAlo[l2]);
            }
            asm volatile("s_waitcnt vmcnt(0)" ::: "memory");
            __syncthreads();

            bf16x8 ah[4], al[4], bh[4], bl[4];
#pragma unroll
            for (int i = 0; i < 4; i++) {
                ah[i] = *(const bf16x8*)&lsAhi[(ar + i * 16) * 32 + fo];
                al[i] = *(const bf16x8*)&lsAlo[(ar + i * 16) * 32 + fo];
                bh[i] = *(const bf16x8*)&lsBhi[(br + i * 16) * 32 + fo];
                bl[i] = *(const bf16x8*)&lsBlo[(br + i * 16) * 32 + fo];
            }
#pragma unroll
            for (int i = 0; i < 4; i++)
#pragma unroll
                for (int j = 0; j < 4; j++) {
                    acc[i][j] = __builtin_amdgcn_mfma_f32_16x16x32_bf16(ah[i], bh[j], acc[i][j], 0, 0, 0);
                    acc[i][j] = __builtin_amdgcn_mfma_f32_16x16x32_bf16(ah[i], bl[j], acc[i][j], 0, 0, 0);
                    acc[i][j] = __builtin_amdgcn_mfma_f32_16x16x32_bf16(al[i], bh[j], acc[i][j], 0, 0, 0);
                }
        }
    }

    // Epilogue: x = acc + dec_a[b][n]; energy += tanh(x)*v[n], reduced over head's A-dim
    const int h = ntile >> 2;
    const int kg = lane >> 4;
    float dv[4], vv[4];
#pragma unroll
    for (int j = 0; j < 4; j++) {
        int ng = n0 + wn * 64 + j * 16 + (lane & 15);
        dv[j] = dec_a[(size_t)b * NN + ng];
        vv[j] = vvec[ng];
    }
#pragma unroll
    for (int i = 0; i < 4; i++) {
        float part[4] = {0.f, 0.f, 0.f, 0.f};
#pragma unroll
        for (int j = 0; j < 4; j++)
#pragma unroll
            for (int r = 0; r < 4; r++)
                part[r] += tanh_fast(acc[i][j][r] + dv[j]) * vv[j];
#pragma unroll
        for (int r = 0; r < 4; r++) {
            float s = part[r];
            s += __shfl_xor(s, 1, 64);
            s += __shfl_xor(s, 2, 64);
            s += __shfl_xor(s, 4, 64);
            s += __shfl_xor(s, 8, 64);
            if ((lane & 15) == 0) {
                int t = m0 + wm * 64 + i * 16 + kg * 4 + r;
                if (t < TT)
                    atomicAdd(&energy[((size_t)b * HH + h) * TP + t], s);
            }
        }
    }
}

// ---------- masked softmax over time (replicates energy * (+1 / -1024) mask) ----------
__global__ __launch_bounds__(1024) void k_softmax(const float* __restrict__ energy,
                                                  const int* __restrict__ x_lens,
                                                  float* __restrict__ aw) {
    const int b = blockIdx.x >> 2, h = blockIdx.x & 3;
    const int tid = threadIdx.x;
    __shared__ float sE[TT];
    __shared__ float red[1024];
    const int xlen = x_lens[b];
    float lmax = -3.4e38f;
    for (int t = tid; t < TT; t += 1024) {
        float e = energy[((size_t)b * HH + h) * TP + t];
        float m = (t < xlen) ? e : e * -1024.0f;
        sE[t] = m;
        lmax = fmaxf(lmax, m);
    }
    red[tid] = lmax; __syncthreads();
    for (int s = 512; s > 0; s >>= 1) { if (tid < s) red[tid] = fmaxf(red[tid], red[tid + s]); __syncthreads(); }
    float mx = red[0]; __syncthreads();
    float lsum = 0.f;
    for (int t = tid; t < TT; t += 1024) {
        float ex = __expf(sE[t] - mx);     // e^x (fast); r4's *log2e scaling was a bug
        sE[t] = ex; lsum += ex;
    }
    red[tid] = lsum; __syncthreads();
    for (int s = 512; s > 0; s >>= 1) { if (tid < s) red[tid] += red[tid + s]; __syncthreads(); }
    float rs = 1.0f / red[0];
    for (int t = tid; t < TT; t += 1024)
        aw[((size_t)b * TT + t) * HH + h] = sE[t] * rs;
}

// ---------- ctx_h[b][h][e] = sum_t aw[b][t][h] * enc[b][t][e] ----------
// Chunks whose aw stripe is exactly 0 (fp32 softmax underflow for valid rows when
// padded logits dominate) are skipped -- exact, since their contribution is +0.
__global__ __launch_bounds__(512) void k_ctx(const float* __restrict__ enc,
                                             const float* __restrict__ aw,
                                             float* __restrict__ ctx_h) {
    const int chunk = blockIdx.x, b = blockIdx.y;
    const int t0 = chunk * 128;
    const int nt = (TT - t0 < 128) ? (TT - t0) : 128;
    __shared__ float sA[128 * 4];
    __shared__ int s_nz;
    const int tid = threadIdx.x;
    if (tid == 0) s_nz = 0;
    __syncthreads();
    for (int i = tid; i < nt * 4; i += 512) {
        float w = aw[((size_t)b * TT + t0) * HH + i];
        sA[i] = w;
        if (w != 0.f) s_nz = 1;            // race-benign: all writers store 1
    }
    __syncthreads();
    if (!s_nz) return;
    float a0 = 0.f, a1 = 0.f, a2 = 0.f, a3 = 0.f;
    const float* ep = enc + ((size_t)b * TT + t0) * EE + tid;
    if (nt == 128) {
#pragma unroll 8
        for (int tt = 0; tt < 128; ++tt) {
            float ev = ep[(size_t)tt * EE];
            a0 += sA[tt * 4 + 0] * ev; a1 += sA[tt * 4 + 1] * ev;
            a2 += sA[tt * 4 + 2] * ev; a3 += sA[tt * 4 + 3] * ev;
        }
    } else {
        for (int tt = 0; tt < nt; ++tt) {
            float ev = ep[(size_t)tt * EE];
            a0 += sA[tt * 4 + 0] * ev; a1 += sA[tt * 4 + 1] * ev;
            a2 += sA[tt * 4 + 2] * ev; a3 += sA[tt * 4 + 3] * ev;
        }
    }
    atomicAdd(&ctx_h[((size_t)b * HH + 0) * EE + tid], a0);
    atomicAdd(&ctx_h[((size_t)b * HH + 1) * EE + tid], a1);
    atomicAdd(&ctx_h[((size_t)b * HH + 2) * EE + tid], a2);
    atomicAdd(&ctx_h[((size_t)b * HH + 3) * EE + tid], a3);
}

// ---------- ctx = ctx_h @ w_mha + b_mha ----------
__global__ __launch_bounds__(256) void k_mha(const float* __restrict__ ctx_h,
                                             const float* __restrict__ w_mha,
                                             const float* __restrict__ b_mha,
                                             float* __restrict__ out) {
    __shared__ float sred[256];
    const int tid = threadIdx.x;
    const int b  = blockIdx.x >> 2;
    const int eo = ((blockIdx.x & 3) << 7) + (tid & 127);
    const int kg = tid >> 7;                   // 0..1, 1024 k each
    const float* c = ctx_h + (size_t)b * NN + kg * 1024;
    const float* w = w_mha + ((size_t)kg * 1024) * EE + eo;
    float acc = 0.f;
#pragma unroll 8
    for (int k = 0; k < 1024; ++k) acc += c[k] * w[(size_t)k * EE];
    sred[tid] = acc;
    __syncthreads();
    if (tid < 128)
        out[(size_t)b * EE + eo] = b_mha[eo] + sred[tid] + sred[tid + 128];
}

extern "C" void kernel_launch(void* const* d_in, const int* in_sizes, int n_in,
                              void* d_out, int out_size, void* d_ws, size_t ws_size,
                              hipStream_t stream) {
    (void)in_sizes; (void)n_in; (void)out_size;
    const float* enc    = (const float*)d_in[0];
    const int*   xlen   = (const int*)d_in[1];
    const float* dec    = (const float*)d_in[2];
    const float* aw_in  = (const float*)d_in[3];
    const float* w_enc  = (const float*)d_in[4];
    const float* b_enc  = (const float*)d_in[5];
    const float* w_dec  = (const float*)d_in[6];
    const float* w_conv = (const float*)d_in[7];
    const float* convk  = (const float*)d_in[8];
    const float* v      = (const float*)d_in[9];
    const float* w_mha  = (const float*)d_in[10];
    const float* b_mha  = (const float*)d_in[11];
    float* out = (float*)d_out;

    // ws layout (~18.6 MB)
    char* ws = (char*)d_ws;
    unsigned short* Whi = (unsigned short*)ws;                   // 2,359,296 B
    unsigned short* Wlo = (unsigned short*)(ws + 2359296);       // 2,359,296 B
    unsigned short* Chi = (unsigned short*)(ws + 4718592);       // 6,291,456 B
    unsigned short* Clo = (unsigned short*)(ws + 11010048);      // 6,291,456 B
    float* dec_a  = (float*)(ws + 17301504);                     //   262,144 B
    float* energy = (float*)(ws + 17563648);                     //   786,432 B
    float* ctx_h  = (float*)(ws + 18350080);                     //   262,144 B
    (void)ws_size;

    hipMemsetAsync(energy, 0, 786432 + 262144, stream);  // energy + ctx_h contiguous

    k_prep<<<dim3(PREP_TOTAL), 256, 0, stream>>>(dec, aw_in, w_enc, b_enc,
                                                 w_dec, w_conv, convk,
                                                 Whi, Wlo, Chi, Clo, dec_a);
    k_gemm<<<dim3(6144), 256, 0, stream>>>(enc, Chi, Clo, Whi, Wlo, dec_a, v, xlen, energy);
    k_softmax<<<dim3(BB * HH), 1024, 0, stream>>>(energy, xlen, out + 16384);
    k_ctx <<<dim3(12, BB), 512, 0, stream>>>(enc, out + 16384, ctx_h);
    k_mha <<<dim3(128), 256, 0, stream>>>(ctx_h, w_mha, b_mha, out);
}

// Round 6
// 685.021 us; speedup vs baseline: 1.1534x; 1.1534x over previous
//
#include <hip/hip_runtime.h>
#include <hip/hip_bf16.h>

// Problem constants
#define BB 32
#define TT 1500
#define TP 1536      // T padded to 12*128 for GEMM tiles
#define EE 512
#define HH 4
#define AA 512
#define NN 2048      // H*A
#define CC 10
#define KCONV 201
#define KAUG 576     // 512 enc + 40 conv + 24 zero pad (18 k-steps of 32)

typedef __attribute__((ext_vector_type(8))) __bf16 bf16x8;
typedef __attribute__((ext_vector_type(4))) float f32x4;

// ---------- helpers ----------
__device__ __forceinline__ unsigned short f2bf(float x) {
    unsigned int u = __float_as_uint(x);
    u = (u + 0x7fffu + ((u >> 16) & 1u)) >> 16;   // RNE, inputs always finite
    return (unsigned short)u;
}
__device__ __forceinline__ float bf2f(unsigned short u) {
    return __uint_as_float(((unsigned int)u) << 16);
}
__device__ __forceinline__ void glds16(const void* g, void* l) {
    __builtin_amdgcn_global_load_lds(
        (const __attribute__((address_space(1))) unsigned int*)g,
        (__attribute__((address_space(3))) unsigned int*)l, 16, 0, 0);
}
// tanh(x) = 1 - 2/(e^{2x}+1); saturates correctly at +-inf; abs err ~1e-6.
__device__ __forceinline__ float tanh_fast(float x) {
    float e = __expf(x * 2.0f);
    return fmaf(-2.0f, __builtin_amdgcn_rcpf(e + 1.0f), 1.0f);
}
// packed f32x2 -> bf16x2 (RNE)
__device__ __forceinline__ unsigned int pkbf(float x, float y) {
    float2 f{x, y};
    __hip_bfloat162 h2 = __float22bfloat162_rn(f);
    return *reinterpret_cast<unsigned int*>(&h2);
}
// split pair into packed hi bf16x2 and packed lo (residual) bf16x2
__device__ __forceinline__ void split2(float x, float y, unsigned int& h, unsigned int& l) {
    unsigned short hx = f2bf(x), hy = f2bf(y);
    h = ((unsigned int)hy << 16) | hx;
    l = pkbf(x - bf2f(hx), y - bf2f(hy));
}

// Fused prep kernel: block-range dispatch of 3 phases.
#define PREP_DEC0   0
#define PREP_CONV0  1024
#define PREP_WT0    8704
#define PREP_TOTAL  8992

__global__ __launch_bounds__(256) void k_prep(
    const float* __restrict__ dec_out, const float* __restrict__ aw_step,
    const float* __restrict__ w_enc, const float* __restrict__ b_enc,
    const float* __restrict__ w_dec, const float* __restrict__ w_conv,
    const float* __restrict__ conv_k,
    unsigned short* __restrict__ Whi, unsigned short* __restrict__ Wlo,
    unsigned short* __restrict__ Chi, unsigned short* __restrict__ Clo,
    float* __restrict__ dec_a) {
    __shared__ float sh[64 * 65];   // wt transpose tile; aliased by dec/conv scratch
    const int bid = blockIdx.x;
    const int tid = threadIdx.x;

    if (bid < PREP_CONV0) {
        // ---- dec: dec_a[b][n] = b_enc[n] + sum_d dec[b][d]*w_dec[h][d][a] ----
        const int b  = bid >> 5;
        const int n0 = (bid & 31) * 64;
        const int n  = n0 + (tid & 63);
        const int dg = tid >> 6;                   // 0..3, 128 d each
        const int h  = n >> 9, a = n & 511;
        const float* dp = dec_out + (size_t)b * 512 + dg * 128;
        const float* wp = w_dec + ((size_t)h * 512 + dg * 128) * 512 + a;
        float acc = 0.f;
#pragma unroll 8
        for (int d = 0; d < 128; ++d) acc += dp[d] * wp[(size_t)d * 512];
        sh[tid] = acc;
        __syncthreads();
        if (tid < 64) {
            float tot = sh[tid] + sh[tid + 64] + sh[tid + 128] + sh[tid + 192];
            dec_a[(size_t)b * NN + n0 + tid] = b_enc[n0 + tid] + tot;
        }
    } else if (bid < PREP_WT0) {
        // ---- conv: grouped 1D conv over aw_step -> Chi/Clo[b][t][hc] ----
        int r = bid - PREP_CONV0;                  // 7680 = 6*40*32
        const int tch = r % 6;
        const int hc  = (r / 6) % 40;
        const int b   = r / 240;
        const int h   = hc / 10;
        const int t0  = tch * 256;
        float* sAw = sh;
        for (int i = tid; i < 456; i += 256) {
            int ts = t0 - 100 + i;
            sAw[i] = (ts >= 0 && ts < TT) ? aw_step[((size_t)b * TT + ts) * HH + h] : 0.f;
        }
        __syncthreads();
        int t = t0 + tid;
        if (t < TT) {
            const float* ck = conv_k + (size_t)hc * KCONV;   // uniform index -> s_load
            float acc = 0.f;
#pragma unroll 4
            for (int k = 0; k < KCONV; ++k) acc += sAw[tid + k] * ck[k];
            size_t o = ((size_t)b * TP + t) * 64 + hc;
            unsigned short hi = f2bf(acc);
            Chi[o] = hi; Clo[o] = f2bf(acc - bf2f(hi));
        }
    } else {
        // ---- wt: W planes [N=2048][KAUG], hi/lo; coalesced via LDS transpose ----
        int r = bid - PREP_WT0;                    // 0..287 = 4h * 8a * 9k
        const int h  = r / 72;
        const int rr = r % 72;
        const int at = rr / 9;
        const int kt = rr % 9;
        const int a0 = at * 64;
        if (kt < 8) {
            const int k0 = kt * 64;
#pragma unroll
            for (int it = 0; it < 16; ++it) {
                int kk = it * 4 + (tid >> 6);
                int aa = tid & 63;
                sh[kk * 65 + aa] = w_enc[((size_t)h * 512 + k0 + kk) * 512 + a0 + aa];
            }
            __syncthreads();
#pragma unroll
            for (int it = 0; it < 16; ++it) {
                int nl = it * 4 + (tid >> 6);
                int kk = tid & 63;
                float val = sh[kk * 65 + nl];
                size_t o = ((size_t)h * 512 + a0 + nl) * KAUG + k0 + kk;
                unsigned short hi = f2bf(val);
                Whi[o] = hi; Wlo[o] = f2bf(val - bf2f(hi));
            }
        } else {
            // k in [512,576): conv cols (block-diagonal per head) + zero pad
#pragma unroll
            for (int it = 0; it < 16; ++it) {
                int nl = it * 4 + (tid >> 6);
                int j  = tid & 63;
                float val = 0.f;
                if (j < 40 && (j / 10) == h)
                    val = w_conv[((size_t)h * 10 + (j % 10)) * 512 + a0 + nl];
                size_t o = ((size_t)h * 512 + a0 + nl) * KAUG + 512 + j;
                unsigned short hi = f2bf(val);
                Whi[o] = hi; Wlo[o] = f2bf(val - bf2f(hi));
            }
        }
    }
}

// ---------- fused MFMA GEMM (both paths) + (+dec_a, tanh, *v, reduce-A) -> energy ----------
// LPT block order: mtile DESCENDING so 3-product p-tiles (high mtiles) dispatch first;
// HW round-robins blocks to CUs as they free -> balanced makespan (r5's static per-XCD
// split put all p-tiles on 2 XCDs: 3x makespan). 16 ntiles of a tile stay consecutive
// for temporal enc L2 reuse. enc prefetch issued AFTER the 2nd barrier so the
// compiler's pre-barrier vmcnt(0) drain never waits on it.
__global__ __launch_bounds__(256) void k_gemm(
    const float* __restrict__ enc,
    const unsigned short* __restrict__ Chi, const unsigned short* __restrict__ Clo,
    const unsigned short* __restrict__ Whi, const unsigned short* __restrict__ Wlo,
    const float* __restrict__ dec_a, const float* __restrict__ vvec,
    const int* __restrict__ xl, float* __restrict__ energy) {
    __shared__ unsigned short lsAhi[4096], lsAlo[4096];
    __shared__ unsigned short lsBhi[4096], lsBlo[4096];
    const int id = blockIdx.x;                    // 6144
    const int tile = id >> 4;                     // 0..383
    const int ntile = id & 15;
    const int mtile = 11 - (tile >> 5);           // descending: p-tiles first (LPT)
    const int b = tile & 31;
    const int tid = threadIdx.x;
    const int lane = tid & 63, wave = tid >> 6;
    const int wm = wave >> 1, wn = wave & 1;
    const int m0 = mtile * 128, n0 = ntile * 128;
    const int xlen = xl[b];

    f32x4 acc[4][4];
#pragma unroll
    for (int i = 0; i < 4; i++)
#pragma unroll
        for (int j = 0; j < 4; j++) acc[i][j] = (f32x4){0.f, 0.f, 0.f, 0.f};

    const int row = tid >> 2;
    const int ko  = (tid & 3) * 8;
    const size_t bbase = ((size_t)n0 + row) * KAUG + ko;
    const size_t cbase = ((size_t)b * TP + m0 + row) * 64 + ko;
    const int l1 = tid * 8;                       // wave-uniform + lane*16B
    const int l2 = l1 + 2048;
    const int ar = wm * 64, br = wn * 64;
    const int fo = (lane & 15) * 32 + (lane >> 4) * 8;

    const float* ap0 = enc + ((size_t)b * TT + m0 + row) * 512 + ko;
    const float* ap1 = ap0 + (size_t)64 * 512;

    if (m0 + 128 <= xlen) {
        // ================= v-path: 1-product =================
        float4 fa0 = *(const float4*)(ap0);
        float4 fa1 = *(const float4*)(ap0 + 4);
        float4 fa2 = *(const float4*)(ap1);
        float4 fa3 = *(const float4*)(ap1 + 4);
        for (int ks = 0; ks < 18; ++ks) {
            const int k0 = ks * 32;
            __syncthreads();
            glds16(Whi + bbase + k0,                     &lsBhi[l1]);
            glds16(Whi + bbase + k0 + (size_t)64 * KAUG, &lsBhi[l2]);
            if (ks < 16) {
                uint4 w0, w1;
                w0.x = pkbf(fa0.x, fa0.y); w0.y = pkbf(fa0.z, fa0.w);
                w0.z = pkbf(fa1.x, fa1.y); w0.w = pkbf(fa1.z, fa1.w);
                w1.x = pkbf(fa2.x, fa2.y); w1.y = pkbf(fa2.z, fa2.w);
                w1.z = pkbf(fa3.x, fa3.y); w1.w = pkbf(fa3.z, fa3.w);
                *reinterpret_cast<uint4*>(&lsAhi[l1]) = w0;
                *reinterpret_cast<uint4*>(&lsAhi[l2]) = w1;
            } else {
                glds16(Chi + cbase + (ks - 16) * 32,        &lsAhi[l1]);
                glds16(Chi + cbase + (ks - 16) * 32 + 4096, &lsAhi[l2]);
            }
            asm volatile("s_waitcnt vmcnt(0)" ::: "memory");
            __syncthreads();

            bf16x8 ah[4], bh[4];
#pragma unroll
            for (int i = 0; i < 4; i++) {
                ah[i] = *(const bf16x8*)&lsAhi[(ar + i * 16) * 32 + fo];
                bh[i] = *(const bf16x8*)&lsBhi[(br + i * 16) * 32 + fo];
            }
            // prefetch next enc slab here: hidden under MFMA, outside barrier drain
            if (ks < 15) {
                const int nk = k0 + 32;
                fa0 = *(const float4*)(ap0 + nk);
                fa1 = *(const float4*)(ap0 + nk + 4);
                fa2 = *(const float4*)(ap1 + nk);
                fa3 = *(const float4*)(ap1 + nk + 4);
            }
#pragma unroll
            for (int i = 0; i < 4; i++)
#pragma unroll
                for (int j = 0; j < 4; j++)
                    acc[i][j] = __builtin_amdgcn_mfma_f32_16x16x32_bf16(ah[i], bh[j], acc[i][j], 0, 0, 0);
        }
    } else {
        // ================= p-path: 3-product split-bf16 =================
        const bool g1 = (m0 + row + 64) < TT;     // rows >= 1500 fed zeros
        const float4 z4 = {0.f, 0.f, 0.f, 0.f};
        // wave-uniform: row-group i (rows m0+ar+16i..+16) needs correction only if
        // it contains padded rows (t >= xlen)
        bool corr[4];
#pragma unroll
        for (int i = 0; i < 4; i++) corr[i] = (m0 + ar + i * 16 + 16) > xlen;
        float4 fa0 = *(const float4*)(ap0);
        float4 fa1 = *(const float4*)(ap0 + 4);
        float4 fa2 = g1 ? *(const float4*)(ap1) : z4;
        float4 fa3 = g1 ? *(const float4*)(ap1 + 4) : z4;
        for (int ks = 0; ks < 18; ++ks) {
            const int k0 = ks * 32;
            __syncthreads();
            glds16(Whi + bbase + k0,                     &lsBhi[l1]);
            glds16(Whi + bbase + k0 + (size_t)64 * KAUG, &lsBhi[l2]);
            glds16(Wlo + bbase + k0,                     &lsBlo[l1]);
            glds16(Wlo + bbase + k0 + (size_t)64 * KAUG, &lsBlo[l2]);
            if (ks < 16) {
                uint4 h0, h1, e0, e1;
                split2(fa0.x, fa0.y, h0.x, e0.x); split2(fa0.z, fa0.w, h0.y, e0.y);
                split2(fa1.x, fa1.y, h0.z, e0.z); split2(fa1.z, fa1.w, h0.w, e0.w);
                split2(fa2.x, fa2.y, h1.x, e1.x); split2(fa2.z, fa2.w, h1.y, e1.y);
                split2(fa3.x, fa3.y, h1.z, e1.z); split2(fa3.z, fa3.w, h1.w, e1.w);
                *reinterpret_cast<uint4*>(&lsAhi[l1]) = h0;
                *reinterpret_cast<uint4*>(&lsAhi[l2]) = h1;
                *reinterpret_cast<uint4*>(&lsAlo[l1]) = e0;
                *reinterpret_cast<uint4*>(&lsAlo[l2]) = e1;
            } else {
                glds16(Chi + cbase + (ks - 16) * 32,        &lsAhi[l1]);
                glds16(Chi + cbase + (ks - 16) * 32 + 4096, &lsAhi[l2]);
                glds16(Clo + cbase + (ks - 16) * 32,        &lsAlo[l1]);
                glds16(Clo + cbase + (ks - 16) * 32 + 4096, &lsAlo[l2]);
            }
            asm volatile("s_waitcnt vmcnt(0)" ::: "memory");
            __syncthreads();

            bf16x8 ah[4], al[4], bh[4], bl[4];
#pragma unroll
            for (int i = 0; i < 4; i++) {
                ah[i] = *(const bf16x8*)&lsAhi[(ar + i * 16) * 32 + fo];
                al[i] = *(const bf16x8*)&lsAlo[(ar + i * 16) * 32 + fo];
                bh[i] = *(const bf16x8*)&lsBhi[(br + i * 16) * 32 + fo];
                bl[i] = *(const bf16x8*)&lsBlo[(br + i * 16) * 32 + fo];
            }
            if (ks < 15) {
                const int nk = k0 + 32;
                fa0 = *(const float4*)(ap0 + nk);
                fa1 = *(const float4*)(ap0 + nk + 4);
                fa2 = g1 ? *(const float4*)(ap1 + nk) : z4;
                fa3 = g1 ? *(const float4*)(ap1 + nk + 4) : z4;
            }
#pragma unroll
            for (int i = 0; i < 4; i++) {
#pragma unroll
                for (int j = 0; j < 4; j++)
                    acc[i][j] = __builtin_amdgcn_mfma_f32_16x16x32_bf16(ah[i], bh[j], acc[i][j], 0, 0, 0);
                if (corr[i]) {
#pragma unroll
                    for (int j = 0; j < 4; j++) {
                        acc[i][j] = __builtin_amdgcn_mfma_f32_16x16x32_bf16(ah[i], bl[j], acc[i][j], 0, 0, 0);
                        acc[i][j] = __builtin_amdgcn_mfma_f32_16x16x32_bf16(al[i], bh[j], acc[i][j], 0, 0, 0);
                    }
                }
            }
        }
    }

    // Epilogue: x = acc + dec_a[b][n]; energy += tanh(x)*v[n], reduced over head's A-dim
    const int h = ntile >> 2;
    const int kg = lane >> 4;
    float dv[4], vv[4];
#pragma unroll
    for (int j = 0; j < 4; j++) {
        int ng = n0 + wn * 64 + j * 16 + (lane & 15);
        dv[j] = dec_a[(size_t)b * NN + ng];
        vv[j] = vvec[ng];
    }
#pragma unroll
    for (int i = 0; i < 4; i++) {
        float part[4] = {0.f, 0.f, 0.f, 0.f};
#pragma unroll
        for (int j = 0; j < 4; j++)
#pragma unroll
            for (int r = 0; r < 4; r++)
                part[r] += tanh_fast(acc[i][j][r] + dv[j]) * vv[j];
#pragma unroll
        for (int r = 0; r < 4; r++) {
            float s = part[r];
            s += __shfl_xor(s, 1, 64);
            s += __shfl_xor(s, 2, 64);
            s += __shfl_xor(s, 4, 64);
            s += __shfl_xor(s, 8, 64);
            if ((lane & 15) == 0) {
                int t = m0 + wm * 64 + i * 16 + kg * 4 + r;
                if (t < TT)
                    atomicAdd(&energy[((size_t)b * HH + h) * TP + t], s);
            }
        }
    }
}

// ---------- masked softmax over time (replicates energy * (+1 / -1024) mask) ----------
__global__ __launch_bounds__(1024) void k_softmax(const float* __restrict__ energy,
                                                  const int* __restrict__ x_lens,
                                                  float* __restrict__ aw) {
    const int b = blockIdx.x >> 2, h = blockIdx.x & 3;
    const int tid = threadIdx.x;
    __shared__ float sE[TT];
    __shared__ float red[1024];
    const int xlen = x_lens[b];
    float lmax = -3.4e38f;
    for (int t = tid; t < TT; t += 1024) {
        float e = energy[((size_t)b * HH + h) * TP + t];
        float m = (t < xlen) ? e : e * -1024.0f;
        sE[t] = m;
        lmax = fmaxf(lmax, m);
    }
    red[tid] = lmax; __syncthreads();
    for (int s = 512; s > 0; s >>= 1) { if (tid < s) red[tid] = fmaxf(red[tid], red[tid + s]); __syncthreads(); }
    float mx = red[0]; __syncthreads();
    float lsum = 0.f;
    for (int t = tid; t < TT; t += 1024) {
        float ex = __expf(sE[t] - mx);
        sE[t] = ex; lsum += ex;
    }
    red[tid] = lsum; __syncthreads();
    for (int s = 512; s > 0; s >>= 1) { if (tid < s) red[tid] += red[tid + s]; __syncthreads(); }
    float rs = 1.0f / red[0];
    for (int t = tid; t < TT; t += 1024)
        aw[((size_t)b * TT + t) * HH + h] = sE[t] * rs;
}

// ---------- ctx_h[b][h][e] = sum_t aw[b][t][h] * enc[b][t][e] ----------
__global__ __launch_bounds__(512) void k_ctx(const float* __restrict__ enc,
                                             const float* __restrict__ aw,
                                             float* __restrict__ ctx_h) {
    const int chunk = blockIdx.x, b = blockIdx.y;
    const int t0 = chunk * 128;
    const int nt = (TT - t0 < 128) ? (TT - t0) : 128;
    __shared__ float sA[128 * 4];
    __shared__ int s_nz;
    const int tid = threadIdx.x;
    if (tid == 0) s_nz = 0;
    __syncthreads();
    for (int i = tid; i < nt * 4; i += 512) {
        float w = aw[((size_t)b * TT + t0) * HH + i];
        sA[i] = w;
        if (w != 0.f) s_nz = 1;            // race-benign: all writers store 1
    }
    __syncthreads();
    if (!s_nz) return;
    float a0 = 0.f, a1 = 0.f, a2 = 0.f, a3 = 0.f;
    const float* ep = enc + ((size_t)b * TT + t0) * EE + tid;
    if (nt == 128) {
#pragma unroll 8
        for (int tt = 0; tt < 128; ++tt) {
            float ev = ep[(size_t)tt * EE];
            a0 += sA[tt * 4 + 0] * ev; a1 += sA[tt * 4 + 1] * ev;
            a2 += sA[tt * 4 + 2] * ev; a3 += sA[tt * 4 + 3] * ev;
        }
    } else {
        for (int tt = 0; tt < nt; ++tt) {
            float ev = ep[(size_t)tt * EE];
            a0 += sA[tt * 4 + 0] * ev; a1 += sA[tt * 4 + 1] * ev;
            a2 += sA[tt * 4 + 2] * ev; a3 += sA[tt * 4 + 3] * ev;
        }
    }
    atomicAdd(&ctx_h[((size_t)b * HH + 0) * EE + tid], a0);
    atomicAdd(&ctx_h[((size_t)b * HH + 1) * EE + tid], a1);
    atomicAdd(&ctx_h[((size_t)b * HH + 2) * EE + tid], a2);
    atomicAdd(&ctx_h[((size_t)b * HH + 3) * EE + tid], a3);
}

// ---------- ctx = ctx_h @ w_mha + b_mha ----------
__global__ __launch_bounds__(256) void k_mha(const float* __restrict__ ctx_h,
                                             const float* __restrict__ w_mha,
                                             const float* __restrict__ b_mha,
                                             float* __restrict__ out) {
    __shared__ float sred[256];
    const int tid = threadIdx.x;
    const int b  = blockIdx.x >> 2;
    const int eo = ((blockIdx.x & 3) << 7) + (tid & 127);
    const int kg = tid >> 7;                   // 0..1, 1024 k each
    const float* c = ctx_h + (size_t)b * NN + kg * 1024;
    const float* w = w_mha + ((size_t)kg * 1024) * EE + eo;
    float acc = 0.f;
#pragma unroll 8
    for (int k = 0; k < 1024; ++k) acc += c[k] * w[(size_t)k * EE];
    sred[tid] = acc;
    __syncthreads();
    if (tid < 128)
        out[(size_t)b * EE + eo] = b_mha[eo] + sred[tid] + sred[tid + 128];
}

extern "C" void kernel_launch(void* const* d_in, const int* in_sizes, int n_in,
                              void* d_out, int out_size, void* d_ws, size_t ws_size,
                              hipStream_t stream) {
    (void)in_sizes; (void)n_in; (void)out_size;
    const float* enc    = (const float*)d_in[0];
    const int*   xlen   = (const int*)d_in[1];
    const float* dec    = (const float*)d_in[2];
    const float* aw_in  = (const float*)d_in[3];
    const float* w_enc  = (const float*)d_in[4];
    const float* b_enc  = (const float*)d_in[5];
    const float* w_dec  = (const float*)d_in[6];
    const float* w_conv = (const float*)d_in[7];
    const float* convk  = (const float*)d_in[8];
    const float* v      = (const float*)d_in[9];
    const float* w_mha  = (const float*)d_in[10];
    const float* b_mha  = (const float*)d_in[11];
    float* out = (float*)d_out;

    // ws layout (~18.6 MB)
    char* ws = (char*)d_ws;
    unsigned short* Whi = (unsigned short*)ws;                   // 2,359,296 B
    unsigned short* Wlo = (unsigned short*)(ws + 2359296);       // 2,359,296 B
    unsigned short* Chi = (unsigned short*)(ws + 4718592);       // 6,291,456 B
    unsigned short* Clo = (unsigned short*)(ws + 11010048);      // 6,291,456 B
    float* dec_a  = (float*)(ws + 17301504);                     //   262,144 B
    float* energy = (float*)(ws + 17563648);                     //   786,432 B
    float* ctx_h  = (float*)(ws + 18350080);                     //   262,144 B
    (void)ws_size;

    hipMemsetAsync(energy, 0, 786432 + 262144, stream);  // energy + ctx_h contiguous

    k_prep<<<dim3(PREP_TOTAL), 256, 0, stream>>>(dec, aw_in, w_enc, b_enc,
                                                 w_dec, w_conv, convk,
                                                 Whi, Wlo, Chi, Clo, dec_a);
    k_gemm<<<dim3(6144), 256, 0, stream>>>(enc, Chi, Clo, Whi, Wlo, dec_a, v, xlen, energy);
    k_softmax<<<dim3(BB * HH), 1024, 0, stream>>>(energy, xlen, out + 16384);
    k_ctx <<<dim3(12, BB), 512, 0, stream>>>(enc, out + 16384, ctx_h);
    k_mha <<<dim3(128), 256, 0, stream>>>(ctx_h, w_mha, b_mha, out);
}